// Round 11
// baseline (499.337 us; speedup 1.0000x reference)
//
#include <hip/hip_runtime.h>
#include <hip/hip_cooperative_groups.h>

namespace cg = cooperative_groups;

#define DIM 128
#define CAP 48

typedef _Float16 half8 __attribute__((ext_vector_type(8)));
typedef float f32x4 __attribute__((ext_vector_type(4)));

__device__ __forceinline__ float lrelu(float v) { return v > 0.f ? v : 0.01f * v; }

// ================= phase bodies (shared by coop kernel and fallback kernels) =================

__device__ __forceinline__ void phase1_body(
    int b, int tid, const int* __restrict__ src, const int* __restrict__ dst,
    int* __restrict__ cursor, int* __restrict__ srcs, int e, int eb,
    const float* __restrict__ W1, const float* __restrict__ W2,
    _Float16* __restrict__ Wp1, _Float16* __restrict__ Wp2) {
    if (b < eb) {
        int i = b * 256 + tid;
        if (i < e) {
            int d = dst[i];
            int p = atomicAdd(&cursor[d], 1);
            if (p < CAP) srcs[(size_t)d * CAP + p] = src[i];
        }
        return;
    }
    int bb = b - eb;
    const float* W;
    _Float16* Wp;
    int tid2;
    if (bb < 64) { W = W1; Wp = Wp1; tid2 = bb * 256 + tid; }
    else         { W = W2; Wp = Wp2; tid2 = (bb - 64) * 256 + tid; }
    // frag (kb,cb): lane ll elem j holds W[k=kb*32+(ll>>4)*8+j][nn=cb*16+(ll&15)]
    int jj = tid2 & 7;
    int frag = tid2 >> 3;
    int ll = frag & 63;
    int cb = (frag >> 6) & 7;
    int kb = frag >> 9;
    int k = kb * 32 + ((ll >> 4) << 3) + jj;
    int nn = cb * 16 + (ll & 15);
    Wp[tid2] = (_Float16)W[(size_t)k * DIM + nn];
}

__device__ __forceinline__ void phase2_body(
    int t, int tid, const float* __restrict__ x, const _Float16* __restrict__ Wp1,
    const _Float16* __restrict__ Wp2, const int* __restrict__ cursor,
    _Float16* __restrict__ hs, _Float16* __restrict__ P, int n, _Float16* LS) {
    const int w = tid >> 6, l = tid & 63;
    const int row0 = t * 64;
    const int arow = row0 + w * 16 + (l & 15);
    const int kq = (l >> 4) << 3;
    const bool ok = arow < n;
    const float* xr = &x[(size_t)arow * DIM + kq];

    f32x4 ah[8], ap[8];
#pragma unroll
    for (int cb = 0; cb < 8; ++cb) {
        f32x4 z = {0.f, 0.f, 0.f, 0.f};
        ah[cb] = z; ap[cb] = z;
    }
#pragma unroll
    for (int kb = 0; kb < 4; ++kb) {
        float4 v0 = make_float4(0.f, 0.f, 0.f, 0.f), v1 = v0;
        if (ok) {
            v0 = *(const float4*)&xr[kb * 32];
            v1 = *(const float4*)&xr[kb * 32 + 4];
        }
        half8 a, al;
        a[0] = (_Float16)v0.x; a[1] = (_Float16)v0.y;
        a[2] = (_Float16)v0.z; a[3] = (_Float16)v0.w;
        a[4] = (_Float16)v1.x; a[5] = (_Float16)v1.y;
        a[6] = (_Float16)v1.z; a[7] = (_Float16)v1.w;
#pragma unroll
        for (int ee = 0; ee < 8; ++ee) {
            _Float16 tt = a[ee];
            al[ee] = (tt > (_Float16)0.f) ? tt : tt * (_Float16)0.01f;
        }
#pragma unroll
        for (int cb = 0; cb < 8; ++cb) {
            half8 bf = *(const half8*)&Wp1[((kb * 8 + cb) * 64 + l) * 8];
            ah[cb] = __builtin_amdgcn_mfma_f32_16x16x32_f16(a, bf, ah[cb], 0, 0, 0);
        }
#pragma unroll
        for (int cb = 0; cb < 8; ++cb) {
            half8 bf = *(const half8*)&Wp2[((kb * 8 + cb) * 64 + l) * 8];  // W2 rows 0..127
            ap[cb] = __builtin_amdgcn_mfma_f32_16x16x32_f16(al, bf, ap[cb], 0, 0, 0);
        }
    }
    __syncthreads();  // LS may still be read by previous tile iteration
    const int orow = w * 16 + ((l >> 4) << 2);
    const int oc = l & 15;
#pragma unroll
    for (int reg = 0; reg < 4; ++reg) {
        int grow = row0 + orow + reg;
        float d = (grow < n) ? rsqrtf((float)cursor[grow] + 1.0f) : 0.f;
#pragma unroll
        for (int cb = 0; cb < 8; ++cb)
            LS[(orow + reg) * 136 + cb * 16 + oc] = (_Float16)(ah[cb][reg] * d);
    }
    __syncthreads();
#pragma unroll
    for (int it = 0; it < 4; ++it) {
        int i = it * 256 + tid;
        int r = i >> 4, c = (i & 15) * 8;
        if (row0 + r < n)
            *(half8*)&hs[(size_t)(row0 + r) * DIM + c] = *(const half8*)&LS[r * 136 + c];
    }
    // P: acc-image, 32 halfs/lane contiguous (tile-private)
    _Float16* pl = P + ((size_t)(t * 4 + w) * 64 + l) * 32;
#pragma unroll
    for (int c = 0; c < 4; ++c) {
        half8 o;
#pragma unroll
        for (int ee = 0; ee < 4; ++ee) {
            o[ee]     = (_Float16)ap[2 * c][ee];
            o[4 + ee] = (_Float16)ap[2 * c + 1][ee];
        }
        *(half8*)&pl[c * 8] = o;
    }
}

__device__ __forceinline__ void phase3_body(
    int t, int tid, const _Float16* __restrict__ hs, const int* __restrict__ cursor,
    const int* __restrict__ srcs, const float* __restrict__ b1,
    const _Float16* __restrict__ Wp2, _Float16* P, int n, _Float16* LS) {
    const int w = tid >> 6, l = tid & 63;
    const int row0 = t * 64;
    const int g = tid & 15, gid = tid >> 4;

    // init acc from P (tile-private; fully read before overwrite below)
    f32x4 acc[8];
    const _Float16* pl = P + ((size_t)(t * 4 + w) * 64 + l) * 32;
#pragma unroll
    for (int c = 0; c < 4; ++c) {
        half8 pv = *(const half8*)&pl[c * 8];
#pragma unroll
        for (int ee = 0; ee < 4; ++ee) {
            acc[2 * c][ee]     = (float)pv[ee];
            acc[2 * c + 1][ee] = (float)pv[4 + ee];
        }
    }
    __syncthreads();  // LS may still be read by previous tile iteration
    // gather: 16 lanes per node, 4 sweeps of 16 nodes
#pragma unroll
    for (int it = 0; it < 4; ++it) {
        int node = row0 + it * 16 + gid;
        half8 o = 0;
        if (node < n) {
            int rawc = cursor[node];
            int cnt = rawc > CAP ? CAP : rawc;
            const int* sl = &srcs[(size_t)node * CAP];
            half8 h = *(const half8*)&hs[(size_t)node * DIM + g * 8];
            float a[8];
#pragma unroll
            for (int ee = 0; ee < 8; ++ee) a[ee] = (float)h[ee];
            for (int base = 0; base < cnt; base += 16) {
                int m = cnt - base;
                if (m > 16) m = 16;
                int sidb = (g < m) ? sl[base + g] : 0;
                int j = 0;
                for (; j + 4 <= m; j += 4) {
                    int s0 = __shfl(sidb, j, 16);
                    int s1 = __shfl(sidb, j + 1, 16);
                    int s2 = __shfl(sidb, j + 2, 16);
                    int s3 = __shfl(sidb, j + 3, 16);
                    half8 v0 = *(const half8*)&hs[(size_t)s0 * DIM + g * 8];
                    half8 v1 = *(const half8*)&hs[(size_t)s1 * DIM + g * 8];
                    half8 v2 = *(const half8*)&hs[(size_t)s2 * DIM + g * 8];
                    half8 v3 = *(const half8*)&hs[(size_t)s3 * DIM + g * 8];
#pragma unroll
                    for (int ee = 0; ee < 8; ++ee)
                        a[ee] += (float)v0[ee] + (float)v1[ee] + (float)v2[ee] + (float)v3[ee];
                }
                for (; j + 2 <= m; j += 2) {
                    int s0 = __shfl(sidb, j, 16);
                    int s1 = __shfl(sidb, j + 1, 16);
                    half8 v0 = *(const half8*)&hs[(size_t)s0 * DIM + g * 8];
                    half8 v1 = *(const half8*)&hs[(size_t)s1 * DIM + g * 8];
#pragma unroll
                    for (int ee = 0; ee < 8; ++ee) a[ee] += (float)v0[ee] + (float)v1[ee];
                }
                if (j < m) {
                    int s0 = __shfl(sidb, j, 16);
                    half8 v0 = *(const half8*)&hs[(size_t)s0 * DIM + g * 8];
#pragma unroll
                    for (int ee = 0; ee < 8; ++ee) a[ee] += (float)v0[ee];
                }
            }
            float d = rsqrtf((float)rawc + 1.0f);
            const float4 bb0 = *(const float4*)&b1[g * 8];
            const float4 bb1 = *(const float4*)&b1[g * 8 + 4];
            o[0] = (_Float16)lrelu(fmaf(a[0], d, bb0.x));
            o[1] = (_Float16)lrelu(fmaf(a[1], d, bb0.y));
            o[2] = (_Float16)lrelu(fmaf(a[2], d, bb0.z));
            o[3] = (_Float16)lrelu(fmaf(a[3], d, bb0.w));
            o[4] = (_Float16)lrelu(fmaf(a[4], d, bb1.x));
            o[5] = (_Float16)lrelu(fmaf(a[5], d, bb1.y));
            o[6] = (_Float16)lrelu(fmaf(a[6], d, bb1.z));
            o[7] = (_Float16)lrelu(fmaf(a[7], d, bb1.w));
        }
        // A-frag write: frag = it*4 + (g>>2); lane-in-frag = (g&3)*16 + gid
        *(half8*)&LS[(((it * 4 + (g >> 2)) * 64) + (g & 3) * 16 + gid) * 8] = o;
    }
    __syncthreads();
#pragma unroll
    for (int kb = 0; kb < 4; ++kb) {
        half8 a = *(const half8*)&LS[((w * 4 + kb) * 64 + l) * 8];
#pragma unroll
        for (int cb = 0; cb < 8; ++cb) {
            half8 bf = *(const half8*)&Wp2[(((kb + 4) * 8 + cb) * 64 + l) * 8];  // W2 rows 128..255
            acc[cb] = __builtin_amdgcn_mfma_f32_16x16x32_f16(a, bf, acc[cb], 0, 0, 0);
        }
    }
    __syncthreads();  // Af fully consumed before Hs overwrite
    const int orow = w * 16 + ((l >> 4) << 2);
    const int oc = l & 15;
#pragma unroll
    for (int reg = 0; reg < 4; ++reg) {
        int grow = row0 + orow + reg;
        float d = (grow < n) ? rsqrtf((float)cursor[grow] + 1.0f) : 0.f;
#pragma unroll
        for (int cb = 0; cb < 8; ++cb)
            LS[(orow + reg) * 136 + cb * 16 + oc] = (_Float16)(acc[cb][reg] * d);
    }
    __syncthreads();
    // hs2 (aliases P) coalesced stores
#pragma unroll
    for (int it = 0; it < 4; ++it) {
        int i = it * 256 + tid;
        int r = i >> 4, c = (i & 15) * 8;
        if (row0 + r < n)
            *(half8*)&P[(size_t)(row0 + r) * DIM + c] = *(const half8*)&LS[r * 136 + c];
    }
}

__device__ __forceinline__ void phase4_body(
    int gr, int tid, const _Float16* __restrict__ hs2, const int* __restrict__ cursor,
    const int* __restrict__ srcs, const float* __restrict__ b2,
    const float* __restrict__ wout, const float* __restrict__ bout,
    float* __restrict__ out, int n) {
    const int node = gr * 16 + (tid >> 4);
    const int g = tid & 15;
    if (node >= n) return;
    int rawc = cursor[node];
    int cnt = rawc > CAP ? CAP : rawc;
    const int* sl = &srcs[(size_t)node * CAP];
    half8 h = *(const half8*)&hs2[(size_t)node * DIM + g * 8];
    float a[8];
#pragma unroll
    for (int ee = 0; ee < 8; ++ee) a[ee] = (float)h[ee];
    for (int base = 0; base < cnt; base += 16) {
        int m = cnt - base;
        if (m > 16) m = 16;
        int sidb = (g < m) ? sl[base + g] : 0;
        int j = 0;
        for (; j + 4 <= m; j += 4) {
            int s0 = __shfl(sidb, j, 16);
            int s1 = __shfl(sidb, j + 1, 16);
            int s2 = __shfl(sidb, j + 2, 16);
            int s3 = __shfl(sidb, j + 3, 16);
            half8 v0 = *(const half8*)&hs2[(size_t)s0 * DIM + g * 8];
            half8 v1 = *(const half8*)&hs2[(size_t)s1 * DIM + g * 8];
            half8 v2 = *(const half8*)&hs2[(size_t)s2 * DIM + g * 8];
            half8 v3 = *(const half8*)&hs2[(size_t)s3 * DIM + g * 8];
#pragma unroll
            for (int ee = 0; ee < 8; ++ee)
                a[ee] += (float)v0[ee] + (float)v1[ee] + (float)v2[ee] + (float)v3[ee];
        }
        for (; j + 2 <= m; j += 2) {
            int s0 = __shfl(sidb, j, 16);
            int s1 = __shfl(sidb, j + 1, 16);
            half8 v0 = *(const half8*)&hs2[(size_t)s0 * DIM + g * 8];
            half8 v1 = *(const half8*)&hs2[(size_t)s1 * DIM + g * 8];
#pragma unroll
            for (int ee = 0; ee < 8; ++ee) a[ee] += (float)v0[ee] + (float)v1[ee];
        }
        if (j < m) {
            int s0 = __shfl(sidb, j, 16);
            half8 v0 = *(const half8*)&hs2[(size_t)s0 * DIM + g * 8];
#pragma unroll
            for (int ee = 0; ee < 8; ++ee) a[ee] += (float)v0[ee];
        }
    }
    float d = rsqrtf((float)rawc + 1.0f);
    const float4 bb0 = *(const float4*)&b2[g * 8];
    const float4 bb1 = *(const float4*)&b2[g * 8 + 4];
    const float4 wv0 = *(const float4*)&wout[g * 8];
    const float4 wv1 = *(const float4*)&wout[g * 8 + 4];
    float s = lrelu(fmaf(a[0], d, bb0.x)) * wv0.x + lrelu(fmaf(a[1], d, bb0.y)) * wv0.y +
              lrelu(fmaf(a[2], d, bb0.z)) * wv0.z + lrelu(fmaf(a[3], d, bb0.w)) * wv0.w +
              lrelu(fmaf(a[4], d, bb1.x)) * wv1.x + lrelu(fmaf(a[5], d, bb1.y)) * wv1.y +
              lrelu(fmaf(a[6], d, bb1.z)) * wv1.z + lrelu(fmaf(a[7], d, bb1.w)) * wv1.w;
#pragma unroll
    for (int off = 8; off > 0; off >>= 1) s += __shfl_down(s, off, 16);
    if (g == 0) out[node] = s + bout[0];
}

// ================= cooperative mega-kernel =================

__global__ __launch_bounds__(256, 3) void k_all(
    const float* __restrict__ x, const int* __restrict__ src, const int* __restrict__ dst,
    int* __restrict__ cursor, int* __restrict__ srcs,
    const float* __restrict__ W1, const float* __restrict__ W2,
    _Float16* __restrict__ Wp1, _Float16* __restrict__ Wp2,
    _Float16* __restrict__ hs, _Float16* P,
    const float* __restrict__ b1, const float* __restrict__ b2,
    const float* __restrict__ wout, const float* __restrict__ bout,
    float* __restrict__ out, int n, int e, int eb, int gb) {
    cg::grid_group grid = cg::this_grid();
    __shared__ _Float16 LS[64 * 136];
    const int tid = threadIdx.x;
    const int NB = gridDim.x;

    for (int b = blockIdx.x; b < eb + 192; b += NB)
        phase1_body(b, tid, src, dst, cursor, srcs, e, eb, W1, W2, Wp1, Wp2);
    grid.sync();
    for (int t = blockIdx.x; t < gb; t += NB)
        phase2_body(t, tid, x, Wp1, Wp2, cursor, hs, P, n, LS);
    grid.sync();
    for (int t = blockIdx.x; t < gb; t += NB)
        phase3_body(t, tid, hs, cursor, srcs, b1, Wp2, P, n, LS);
    grid.sync();
    const int ng = (n + 15) >> 4;
    for (int gr = blockIdx.x; gr < ng; gr += NB)
        phase4_body(gr, tid, P, cursor, srcs, b2, wout, bout, out, n);
}

// ================= fallback kernels (R8 structure) =================

__global__ __launch_bounds__(256) void k_prep(
    const int* src, const int* dst, int* cursor, int* srcs, int e, int eb,
    const float* W1, _Float16* Wp1, const float* W2, _Float16* Wp2) {
    phase1_body(blockIdx.x, threadIdx.x, src, dst, cursor, srcs, e, eb, W1, W2, Wp1, Wp2);
}

__global__ __launch_bounds__(256, 2) void k_mm1(
    const float* x, const _Float16* Wp1, const _Float16* Wp2,
    const int* cursor, _Float16* hs, _Float16* P, int n) {
    __shared__ _Float16 LS[64 * 136];
    phase2_body(blockIdx.x, threadIdx.x, x, Wp1, Wp2, cursor, hs, P, n, LS);
}

__global__ __launch_bounds__(256, 2) void k_mm2g(
    const _Float16* hs, const int* cursor, const int* srcs, const float* b1,
    const _Float16* Wp2, _Float16* P, int n) {
    __shared__ _Float16 LS[64 * 136];
    phase3_body(blockIdx.x, threadIdx.x, hs, cursor, srcs, b1, Wp2, P, n, LS);
}

__global__ __launch_bounds__(256) void k_gather2(
    const _Float16* hs2, const int* cursor, const int* srcs, const float* b2,
    const float* wout, const float* bout, float* out, int n) {
    phase4_body(blockIdx.x, threadIdx.x, hs2, cursor, srcs, b2, wout, bout, out, n);
}

extern "C" void kernel_launch(void* const* d_in, const int* in_sizes, int n_in,
                              void* d_out, int out_size, void* d_ws, size_t ws_size,
                              hipStream_t stream) {
    const float* x    = (const float*)d_in[0];
    const int*   ei   = (const int*)d_in[1];
    const float* W1   = (const float*)d_in[2];
    const float* b1   = (const float*)d_in[3];
    const float* W2   = (const float*)d_in[4];
    const float* b2   = (const float*)d_in[5];
    const float* Wout = (const float*)d_in[6];
    const float* bout = (const float*)d_in[7];
    float* out = (float*)d_out;

    const int N = in_sizes[0] / DIM;
    const int E = in_sizes[1] / 2;
    const int* src = ei;      // edge_index[0]
    const int* dst = ei + E;  // edge_index[1]

    const int gb = (N + 63) / 64;
    const int eb = (E + 255) / 256;
    const long long nx = (long long)N * DIM;

    // workspace
    size_t Na = ((size_t)N + 63) & ~(size_t)63;
    int* cursor   = (int*)d_ws;                          // Na
    int* srcs     = cursor + Na;                         // N*CAP
    _Float16* Wp1 = (_Float16*)(srcs + (size_t)N * CAP); // 128*128
    _Float16* Wp2 = Wp1 + 128 * 128;                     // 256*128
    _Float16* hsb = Wp2 + 256 * 128;                     // N*128 (hs)
    _Float16* Pb  = hsb + nx;                            // gb*8192 (P -> hs2)

    (void)hipMemsetAsync(cursor, 0, (size_t)N * sizeof(int), stream);

    // cooperative grid sized from ACTUAL occupancy (R9 failed: guessed grid > co-resident)
    int occ = 0, nCU = 0;
    hipError_t e1 = hipOccupancyMaxActiveBlocksPerMultiprocessor(&occ, (const void*)k_all, 256, 0);
    hipError_t e2 = hipDeviceGetAttribute(&nCU, hipDeviceAttributeMultiprocessorCount, 0);
    hipError_t lerr = hipErrorUnknown;
    if (e1 == hipSuccess && e2 == hipSuccess && occ > 0 && nCU > 0) {
        int grid = occ * nCU;
        void* args[] = {
            (void*)&x, (void*)&src, (void*)&dst,
            (void*)&cursor, (void*)&srcs,
            (void*)&W1, (void*)&W2,
            (void*)&Wp1, (void*)&Wp2,
            (void*)&hsb, (void*)&Pb,
            (void*)&b1, (void*)&b2,
            (void*)&Wout, (void*)&bout,
            (void*)&out, (void*)&N, (void*)&E, (void*)&eb, (void*)&gb
        };
        lerr = hipLaunchCooperativeKernel((const void*)k_all, dim3(grid), dim3(256),
                                          args, 0, stream);
    }
    if (lerr != hipSuccess) {
        // fallback: proven 4-kernel sequence (R8)
        k_prep<<<eb + 192, 256, 0, stream>>>(src, dst, cursor, srcs, E, eb, W1, Wp1, W2, Wp2);
        k_mm1<<<gb, 256, 0, stream>>>(x, Wp1, Wp2, cursor, hsb, Pb, N);
        k_mm2g<<<gb, 256, 0, stream>>>(hsb, cursor, srcs, b1, Wp2, Pb, N);
        k_gather2<<<(N + 15) / 16, 256, 0, stream>>>(Pb, cursor, srcs, b2, Wout, bout, out, N);
    }
}

// Round 12
// 236.940 us; speedup vs baseline: 2.1074x; 2.1074x over previous
//
#include <hip/hip_runtime.h>

#define DIM 128
#define CAP 48

typedef _Float16 half8 __attribute__((ext_vector_type(8)));
typedef float f32x4 __attribute__((ext_vector_type(4)));

__device__ __forceinline__ float lrelu(float v) { return v > 0.f ? v : 0.01f * v; }

// ---------------- prep: CSR-lite fill + pack W1/W2 to MFMA B-frag order ----------------
__global__ __launch_bounds__(256) void k_prep(
    const int* __restrict__ src, const int* __restrict__ dst,
    int* __restrict__ cursor, int* __restrict__ srcs, int e, int eb,
    const float* __restrict__ W1, _Float16* __restrict__ Wp1,
    const float* __restrict__ W2, _Float16* __restrict__ Wp2) {
    int b = blockIdx.x;
    if (b < eb) {
        int i = b * 256 + threadIdx.x;
        if (i < e) {
            int d = dst[i];
            int p = atomicAdd(&cursor[d], 1);
            if (p < CAP) srcs[(size_t)d * CAP + p] = src[i];
        }
        return;
    }
    b -= eb;
    const float* W;
    _Float16* Wp;
    int tid2;
    if (b < 64) { W = W1; Wp = Wp1; tid2 = b * 256 + threadIdx.x; }
    else        { W = W2; Wp = Wp2; tid2 = (b - 64) * 256 + threadIdx.x; }
    // frag (kb,cb): lane l elem j holds W[k=kb*32+(l>>4)*8+j][n=cb*16+(l&15)]
    int jj = tid2 & 7;
    int frag = tid2 >> 3;
    int l = frag & 63;
    int cb = (frag >> 6) & 7;
    int kb = frag >> 9;
    int k = kb * 32 + ((l >> 4) << 3) + jj;
    int nn = cb * 16 + (l & 15);
    Wp[tid2] = (_Float16)W[(size_t)k * DIM + nn];
}

// ---------------- mm1 (fused dual-GEMM, 64-row tiles, fp32 x direct) ----------------
__global__ __launch_bounds__(256, 2) void k_mm1(
    const float* __restrict__ x, const _Float16* __restrict__ Wp1,
    const _Float16* __restrict__ Wp2, const int* __restrict__ cursor,
    _Float16* __restrict__ hs, _Float16* __restrict__ P, int n) {
    __shared__ _Float16 Hs[64 * 136];
    const int tid = threadIdx.x;
    const int w = tid >> 6, l = tid & 63;
    const int row0 = blockIdx.x * 64;
    const int arow = row0 + w * 16 + (l & 15);
    const int kq = (l >> 4) << 3;
    const bool ok = arow < n;
    const float* xr = &x[(size_t)arow * DIM + kq];

    f32x4 ah[8], ap[8];
#pragma unroll
    for (int cb = 0; cb < 8; ++cb) {
        f32x4 z = {0.f, 0.f, 0.f, 0.f};
        ah[cb] = z; ap[cb] = z;
    }
#pragma unroll
    for (int kb = 0; kb < 4; ++kb) {
        float4 v0 = make_float4(0.f, 0.f, 0.f, 0.f), v1 = v0;
        if (ok) {
            v0 = *(const float4*)&xr[kb * 32];
            v1 = *(const float4*)&xr[kb * 32 + 4];
        }
        half8 a, al;
        a[0] = (_Float16)v0.x; a[1] = (_Float16)v0.y;
        a[2] = (_Float16)v0.z; a[3] = (_Float16)v0.w;
        a[4] = (_Float16)v1.x; a[5] = (_Float16)v1.y;
        a[6] = (_Float16)v1.z; a[7] = (_Float16)v1.w;
#pragma unroll
        for (int e = 0; e < 8; ++e) {
            _Float16 t = a[e];
            al[e] = (t > (_Float16)0.f) ? t : t * (_Float16)0.01f;
        }
#pragma unroll
        for (int cb = 0; cb < 8; ++cb) {
            half8 bf = *(const half8*)&Wp1[((kb * 8 + cb) * 64 + l) * 8];
            ah[cb] = __builtin_amdgcn_mfma_f32_16x16x32_f16(a, bf, ah[cb], 0, 0, 0);
        }
#pragma unroll
        for (int cb = 0; cb < 8; ++cb) {
            half8 bf = *(const half8*)&Wp2[((kb * 8 + cb) * 64 + l) * 8];  // W2 rows 0..127
            ap[cb] = __builtin_amdgcn_mfma_f32_16x16x32_f16(al, bf, ap[cb], 0, 0, 0);
        }
    }
    const int orow = w * 16 + ((l >> 4) << 2);
    const int oc = l & 15;
#pragma unroll
    for (int reg = 0; reg < 4; ++reg) {
        int grow = row0 + orow + reg;
        float d = (grow < n) ? rsqrtf((float)cursor[grow] + 1.0f) : 0.f;
#pragma unroll
        for (int cb = 0; cb < 8; ++cb)
            Hs[(orow + reg) * 136 + cb * 16 + oc] = (_Float16)(ah[cb][reg] * d);
    }
    __syncthreads();
#pragma unroll
    for (int it = 0; it < 4; ++it) {
        int i = it * 256 + tid;
        int r = i >> 4, c = (i & 15) * 8;
        if (row0 + r < n)
            *(half8*)&hs[(size_t)(row0 + r) * DIM + c] = *(const half8*)&Hs[r * 136 + c];
    }
    _Float16* pl = P + ((size_t)(blockIdx.x * 4 + w) * 64 + l) * 32;
#pragma unroll
    for (int c = 0; c < 4; ++c) {
        half8 o;
#pragma unroll
        for (int e = 0; e < 4; ++e) {
            o[e]     = (_Float16)ap[2 * c][e];
            o[4 + e] = (_Float16)ap[2 * c + 1][e];
        }
        *(half8*)&pl[c * 8] = o;
    }
}

// ---------------- mm2g: fused gather1 + GEMM2-half ----------------
// gather with 4-node batched head-loads: cursor/srcs-slice/self-row for all 4 sweeps
// issued before any ladder -> one latency chain instead of four.
__global__ __launch_bounds__(256, 2) void k_mm2g(
    const _Float16* __restrict__ hs, const int* __restrict__ cursor,
    const int* __restrict__ srcs, const float* __restrict__ b1,
    const _Float16* __restrict__ Wp2, const _Float16* __restrict__ P,
    _Float16* __restrict__ hs2, int n) {
    __shared__ _Float16 LS[64 * 136];  // Af = first 8192 halfs; reused as Hs
    const int tid = threadIdx.x;
    const int w = tid >> 6, l = tid & 63;
    const int g = tid & 15, gid = tid >> 4;
    const int row0 = blockIdx.x * 64;

    // init acc from P (block-private; fully read before first barrier)
    f32x4 acc[8];
    const _Float16* pl = P + ((size_t)(blockIdx.x * 4 + w) * 64 + l) * 32;
#pragma unroll
    for (int c = 0; c < 4; ++c) {
        half8 pv = *(const half8*)&pl[c * 8];
#pragma unroll
        for (int e = 0; e < 4; ++e) {
            acc[2 * c][e]     = (float)pv[e];
            acc[2 * c + 1][e] = (float)pv[4 + e];
        }
    }

    // batched head loads for 4 sweeps (independent, all in flight together)
    int rawc4[4], sid4[4];
    half8 h4[4];
#pragma unroll
    for (int it = 0; it < 4; ++it) {
        int node = row0 + it * 16 + gid;
        bool okn = node < n;
        rawc4[it] = okn ? cursor[node] : 0;
        sid4[it] = okn ? srcs[(size_t)node * CAP + g] : 0;  // g<16<=CAP in-bounds; masked later
        h4[it] = okn ? *(const half8*)&hs[(size_t)node * DIM + g * 8] : (half8)0;
    }

#pragma unroll
    for (int it = 0; it < 4; ++it) {
        int node = row0 + it * 16 + gid;
        half8 o = 0;
        if (node < n) {
            int rawc = rawc4[it];
            int cnt = rawc > CAP ? CAP : rawc;
            float a[8];
#pragma unroll
            for (int e = 0; e < 8; ++e) a[e] = (float)h4[it][e];
            // first <=16 edges use the preloaded slice
            {
                int m = cnt > 16 ? 16 : cnt;
                int sidb = sid4[it];
                int j = 0;
                for (; j + 4 <= m; j += 4) {
                    int s0 = __shfl(sidb, j, 16);
                    int s1 = __shfl(sidb, j + 1, 16);
                    int s2 = __shfl(sidb, j + 2, 16);
                    int s3 = __shfl(sidb, j + 3, 16);
                    half8 v0 = *(const half8*)&hs[(size_t)s0 * DIM + g * 8];
                    half8 v1 = *(const half8*)&hs[(size_t)s1 * DIM + g * 8];
                    half8 v2 = *(const half8*)&hs[(size_t)s2 * DIM + g * 8];
                    half8 v3 = *(const half8*)&hs[(size_t)s3 * DIM + g * 8];
#pragma unroll
                    for (int e = 0; e < 8; ++e)
                        a[e] += (float)v0[e] + (float)v1[e] + (float)v2[e] + (float)v3[e];
                }
                for (; j + 2 <= m; j += 2) {
                    int s0 = __shfl(sidb, j, 16);
                    int s1 = __shfl(sidb, j + 1, 16);
                    half8 v0 = *(const half8*)&hs[(size_t)s0 * DIM + g * 8];
                    half8 v1 = *(const half8*)&hs[(size_t)s1 * DIM + g * 8];
#pragma unroll
                    for (int e = 0; e < 8; ++e) a[e] += (float)v0[e] + (float)v1[e];
                }
                if (j < m) {
                    int s0 = __shfl(sidb, j, 16);
                    half8 v0 = *(const half8*)&hs[(size_t)s0 * DIM + g * 8];
#pragma unroll
                    for (int e = 0; e < 8; ++e) a[e] += (float)v0[e];
                }
            }
            // rare tail (cnt > 16)
            const int* sl = &srcs[(size_t)node * CAP];
            for (int base = 16; base < cnt; base += 16) {
                int m = cnt - base;
                if (m > 16) m = 16;
                int sidb = (g < m) ? sl[base + g] : 0;
                for (int j = 0; j < m; ++j) {
                    int s0 = __shfl(sidb, j, 16);
                    half8 v0 = *(const half8*)&hs[(size_t)s0 * DIM + g * 8];
#pragma unroll
                    for (int e = 0; e < 8; ++e) a[e] += (float)v0[e];
                }
            }
            float d = rsqrtf((float)rawc + 1.0f);
            const float4 bb0 = *(const float4*)&b1[g * 8];
            const float4 bb1 = *(const float4*)&b1[g * 8 + 4];
            o[0] = (_Float16)lrelu(fmaf(a[0], d, bb0.x));
            o[1] = (_Float16)lrelu(fmaf(a[1], d, bb0.y));
            o[2] = (_Float16)lrelu(fmaf(a[2], d, bb0.z));
            o[3] = (_Float16)lrelu(fmaf(a[3], d, bb0.w));
            o[4] = (_Float16)lrelu(fmaf(a[4], d, bb1.x));
            o[5] = (_Float16)lrelu(fmaf(a[5], d, bb1.y));
            o[6] = (_Float16)lrelu(fmaf(a[6], d, bb1.z));
            o[7] = (_Float16)lrelu(fmaf(a[7], d, bb1.w));
        }
        // A-frag write: frag = it*4 + (g>>2); lane-in-frag = (g&3)*16 + gid
        *(half8*)&LS[(((it * 4 + (g >> 2)) * 64) + (g & 3) * 16 + gid) * 8] = o;
    }
    __syncthreads();

#pragma unroll
    for (int kb = 0; kb < 4; ++kb) {
        half8 a = *(const half8*)&LS[((w * 4 + kb) * 64 + l) * 8];
#pragma unroll
        for (int cb = 0; cb < 8; ++cb) {
            half8 bf = *(const half8*)&Wp2[(((kb + 4) * 8 + cb) * 64 + l) * 8];  // W2 rows 128..255
            acc[cb] = __builtin_amdgcn_mfma_f32_16x16x32_f16(a, bf, acc[cb], 0, 0, 0);
        }
    }
    __syncthreads();  // Af consumed before Hs overwrite
    const int orow = w * 16 + ((l >> 4) << 2);
    const int oc = l & 15;
#pragma unroll
    for (int reg = 0; reg < 4; ++reg) {
        int grow = row0 + orow + reg;
        float d = (grow < n) ? rsqrtf((float)cursor[grow] + 1.0f) : 0.f;
#pragma unroll
        for (int cb = 0; cb < 8; ++cb)
            LS[(orow + reg) * 136 + cb * 16 + oc] = (_Float16)(acc[cb][reg] * d);
    }
    __syncthreads();
#pragma unroll
    for (int it = 0; it < 4; ++it) {
        int i = it * 256 + tid;
        int r = i >> 4, c = (i & 15) * 8;
        if (row0 + r < n)
            *(half8*)&hs2[(size_t)(row0 + r) * DIM + c] = *(const half8*)&LS[r * 136 + c];
    }
}

// ---------------- gather2 + final projection (4-node batched, 64 nodes/block) ----------------
__global__ __launch_bounds__(256) void k_gather2(
    const _Float16* __restrict__ hs2, const int* __restrict__ cursor,
    const int* __restrict__ srcs, const float* __restrict__ b2,
    const float* __restrict__ wout, const float* __restrict__ bout,
    float* __restrict__ out, int n) {
    const int tid = threadIdx.x;
    const int g = tid & 15, gid = tid >> 4;
    const int row0 = blockIdx.x * 64;

    int rawc4[4], sid4[4];
    half8 h4[4];
#pragma unroll
    for (int it = 0; it < 4; ++it) {
        int node = row0 + it * 16 + gid;
        bool okn = node < n;
        rawc4[it] = okn ? cursor[node] : 0;
        sid4[it] = okn ? srcs[(size_t)node * CAP + g] : 0;
        h4[it] = okn ? *(const half8*)&hs2[(size_t)node * DIM + g * 8] : (half8)0;
    }

#pragma unroll
    for (int it = 0; it < 4; ++it) {
        int node = row0 + it * 16 + gid;
        if (node >= n) continue;
        int rawc = rawc4[it];
        int cnt = rawc > CAP ? CAP : rawc;
        float a[8];
#pragma unroll
        for (int e = 0; e < 8; ++e) a[e] = (float)h4[it][e];
        {
            int m = cnt > 16 ? 16 : cnt;
            int sidb = sid4[it];
            int j = 0;
            for (; j + 4 <= m; j += 4) {
                int s0 = __shfl(sidb, j, 16);
                int s1 = __shfl(sidb, j + 1, 16);
                int s2 = __shfl(sidb, j + 2, 16);
                int s3 = __shfl(sidb, j + 3, 16);
                half8 v0 = *(const half8*)&hs2[(size_t)s0 * DIM + g * 8];
                half8 v1 = *(const half8*)&hs2[(size_t)s1 * DIM + g * 8];
                half8 v2 = *(const half8*)&hs2[(size_t)s2 * DIM + g * 8];
                half8 v3 = *(const half8*)&hs2[(size_t)s3 * DIM + g * 8];
#pragma unroll
                for (int e = 0; e < 8; ++e)
                    a[e] += (float)v0[e] + (float)v1[e] + (float)v2[e] + (float)v3[e];
            }
            for (; j + 2 <= m; j += 2) {
                int s0 = __shfl(sidb, j, 16);
                int s1 = __shfl(sidb, j + 1, 16);
                half8 v0 = *(const half8*)&hs2[(size_t)s0 * DIM + g * 8];
                half8 v1 = *(const half8*)&hs2[(size_t)s1 * DIM + g * 8];
#pragma unroll
                for (int e = 0; e < 8; ++e) a[e] += (float)v0[e] + (float)v1[e];
            }
            if (j < m) {
                int s0 = __shfl(sidb, j, 16);
                half8 v0 = *(const half8*)&hs2[(size_t)s0 * DIM + g * 8];
#pragma unroll
                for (int e = 0; e < 8; ++e) a[e] += (float)v0[e];
            }
        }
        const int* sl = &srcs[(size_t)node * CAP];
        for (int base = 16; base < cnt; base += 16) {
            int m = cnt - base;
            if (m > 16) m = 16;
            int sidb = (g < m) ? sl[base + g] : 0;
            for (int j = 0; j < m; ++j) {
                int s0 = __shfl(sidb, j, 16);
                half8 v0 = *(const half8*)&hs2[(size_t)s0 * DIM + g * 8];
#pragma unroll
                for (int e = 0; e < 8; ++e) a[e] += (float)v0[e];
            }
        }
        float d = rsqrtf((float)rawc + 1.0f);
        const float4 bb0 = *(const float4*)&b2[g * 8];
        const float4 bb1 = *(const float4*)&b2[g * 8 + 4];
        const float4 wv0 = *(const float4*)&wout[g * 8];
        const float4 wv1 = *(const float4*)&wout[g * 8 + 4];
        float s = lrelu(fmaf(a[0], d, bb0.x)) * wv0.x + lrelu(fmaf(a[1], d, bb0.y)) * wv0.y +
                  lrelu(fmaf(a[2], d, bb0.z)) * wv0.z + lrelu(fmaf(a[3], d, bb0.w)) * wv0.w +
                  lrelu(fmaf(a[4], d, bb1.x)) * wv1.x + lrelu(fmaf(a[5], d, bb1.y)) * wv1.y +
                  lrelu(fmaf(a[6], d, bb1.z)) * wv1.z + lrelu(fmaf(a[7], d, bb1.w)) * wv1.w;
#pragma unroll
        for (int off = 8; off > 0; off >>= 1) s += __shfl_down(s, off, 16);
        if (g == 0) out[node] = s + bout[0];
    }
}

extern "C" void kernel_launch(void* const* d_in, const int* in_sizes, int n_in,
                              void* d_out, int out_size, void* d_ws, size_t ws_size,
                              hipStream_t stream) {
    const float* x    = (const float*)d_in[0];
    const int*   ei   = (const int*)d_in[1];
    const float* W1   = (const float*)d_in[2];
    const float* b1   = (const float*)d_in[3];
    const float* W2   = (const float*)d_in[4];
    const float* b2   = (const float*)d_in[5];
    const float* Wout = (const float*)d_in[6];
    const float* bout = (const float*)d_in[7];
    float* out = (float*)d_out;

    const int N = in_sizes[0] / DIM;
    const int E = in_sizes[1] / 2;
    const int* src = ei;      // edge_index[0]
    const int* dst = ei + E;  // edge_index[1]

    const int gb = (N + 63) / 64;
    const int eb = (E + 255) / 256;
    const long long nx = (long long)N * DIM;

    // workspace
    size_t Na = ((size_t)N + 63) & ~(size_t)63;
    int* cursor   = (int*)d_ws;                          // Na
    int* srcs     = cursor + Na;                         // N*CAP
    _Float16* Wp1 = (_Float16*)(srcs + (size_t)N * CAP); // 128*128
    _Float16* Wp2 = Wp1 + 128 * 128;                     // 256*128
    _Float16* hsb = Wp2 + 256 * 128;                     // N*128 (hs)
    _Float16* Pb  = hsb + nx;                            // gb*8192 (P -> hs2)

    (void)hipMemsetAsync(cursor, 0, (size_t)N * sizeof(int), stream);
    k_prep<<<eb + 192, 256, 0, stream>>>(src, dst, cursor, srcs, E, eb, W1, Wp1, W2, Wp2);
    k_mm1<<<gb, 256, 0, stream>>>(x, Wp1, Wp2, cursor, hsb, Pb, N);
    k_mm2g<<<gb, 256, 0, stream>>>(hsb, cursor, srcs, b1, Wp2, Pb, Pb, N);
    k_gather2<<<gb, 256, 0, stream>>>(Pb, cursor, srcs, b2, Wout, bout, out, N);
}

// Round 13
// 231.852 us; speedup vs baseline: 2.1537x; 1.0219x over previous
//
#include <hip/hip_runtime.h>

#define DIM 128
#define CAP 48

typedef _Float16 half8 __attribute__((ext_vector_type(8)));
typedef float f32x4 __attribute__((ext_vector_type(4)));

__device__ __forceinline__ float lrelu(float v) { return v > 0.f ? v : 0.01f * v; }

// ---------------- prep: CSR-lite fill + pack W1/W2 to MFMA B-frag order ----------------
__global__ __launch_bounds__(256) void k_prep(
    const int* __restrict__ src, const int* __restrict__ dst,
    int* __restrict__ cursor, int* __restrict__ srcs, int e, int eb,
    const float* __restrict__ W1, _Float16* __restrict__ Wp1,
    const float* __restrict__ W2, _Float16* __restrict__ Wp2) {
    int b = blockIdx.x;
    if (b < eb) {
        int i = b * 256 + threadIdx.x;
        if (i < e) {
            int d = dst[i];
            int p = atomicAdd(&cursor[d], 1);
            if (p < CAP) srcs[(size_t)d * CAP + p] = src[i];
        }
        return;
    }
    b -= eb;
    const float* W;
    _Float16* Wp;
    int tid2;
    if (b < 64) { W = W1; Wp = Wp1; tid2 = b * 256 + threadIdx.x; }
    else        { W = W2; Wp = Wp2; tid2 = (b - 64) * 256 + threadIdx.x; }
    // frag (kb,cb): lane l elem j holds W[k=kb*32+(l>>4)*8+j][n=cb*16+(l&15)]
    int jj = tid2 & 7;
    int frag = tid2 >> 3;
    int l = frag & 63;
    int cb = (frag >> 6) & 7;
    int kb = frag >> 9;
    int k = kb * 32 + ((l >> 4) << 3) + jj;
    int nn = cb * 16 + (l & 15);
    Wp[tid2] = (_Float16)W[(size_t)k * DIM + nn];
}

// ---------------- mm1 (fused dual-GEMM, 64-row tiles, LDS-staged B) ----------------
// hs = f16((x@W1)*dinv)  row-major (LDS transpose);  P = f16(lrelu(x)@W2[0:128,:]) acc-image.
__global__ __launch_bounds__(256, 2) void k_mm1(
    const float* __restrict__ x, const _Float16* __restrict__ Wp1,
    const _Float16* __restrict__ Wp2, const int* __restrict__ cursor,
    _Float16* __restrict__ hs, _Float16* __restrict__ P, int n) {
    __shared__ _Float16 WS[16384];  // 32KB: Wp1 frags -> Wp2-low frags -> Hs transpose
    const int tid = threadIdx.x;
    const int w = tid >> 6, l = tid & 63;
    const int row0 = blockIdx.x * 64;
    const int arow = row0 + w * 16 + (l & 15);
    const int kq = (l >> 4) << 3;
    const bool ok = arow < n;
    const float* xr = &x[(size_t)arow * DIM + kq];

    // hoist all 8 independent x loads (A-frags for all 4 kb)
    float4 xv[8];
#pragma unroll
    for (int kb = 0; kb < 4; ++kb) {
        float4 z = make_float4(0.f, 0.f, 0.f, 0.f);
        xv[2 * kb]     = ok ? *(const float4*)&xr[kb * 32]     : z;
        xv[2 * kb + 1] = ok ? *(const float4*)&xr[kb * 32 + 4] : z;
    }
    // stage Wp1 frags (coalesced 16B/lane)
#pragma unroll
    for (int i = 0; i < 8; ++i) {
        int idx = i * 256 + tid;
        *(half8*)&WS[idx * 8] = *(const half8*)&Wp1[(size_t)idx * 8];
    }
    __syncthreads();

    half8 a[4];
#pragma unroll
    for (int kb = 0; kb < 4; ++kb) {
        half8 t;
        t[0] = (_Float16)xv[2 * kb].x; t[1] = (_Float16)xv[2 * kb].y;
        t[2] = (_Float16)xv[2 * kb].z; t[3] = (_Float16)xv[2 * kb].w;
        t[4] = (_Float16)xv[2 * kb + 1].x; t[5] = (_Float16)xv[2 * kb + 1].y;
        t[6] = (_Float16)xv[2 * kb + 1].z; t[7] = (_Float16)xv[2 * kb + 1].w;
        a[kb] = t;
    }

    f32x4 ah[8];
#pragma unroll
    for (int cb = 0; cb < 8; ++cb) { f32x4 z = {0.f, 0.f, 0.f, 0.f}; ah[cb] = z; }
#pragma unroll
    for (int kb = 0; kb < 4; ++kb)
#pragma unroll
        for (int cb = 0; cb < 8; ++cb) {
            half8 bf = *(const half8*)&WS[((kb * 8 + cb) * 64 + l) * 8];
            ah[cb] = __builtin_amdgcn_mfma_f32_16x16x32_f16(a[kb], bf, ah[cb], 0, 0, 0);
        }
    __syncthreads();
    // restage: Wp2 rows 0..127 (frags 0..31 of Wp2)
#pragma unroll
    for (int i = 0; i < 8; ++i) {
        int idx = i * 256 + tid;
        *(half8*)&WS[idx * 8] = *(const half8*)&Wp2[(size_t)idx * 8];
    }
    __syncthreads();

    f32x4 ap[8];
#pragma unroll
    for (int cb = 0; cb < 8; ++cb) { f32x4 z = {0.f, 0.f, 0.f, 0.f}; ap[cb] = z; }
#pragma unroll
    for (int kb = 0; kb < 4; ++kb) {
        half8 al;
#pragma unroll
        for (int e = 0; e < 8; ++e) {
            _Float16 t = a[kb][e];
            al[e] = (t > (_Float16)0.f) ? t : t * (_Float16)0.01f;
        }
#pragma unroll
        for (int cb = 0; cb < 8; ++cb) {
            half8 bf = *(const half8*)&WS[((kb * 8 + cb) * 64 + l) * 8];
            ap[cb] = __builtin_amdgcn_mfma_f32_16x16x32_f16(al, bf, ap[cb], 0, 0, 0);
        }
    }
    __syncthreads();  // all WS reads done; reuse as Hs (needs 8704 < 16384 halfs)
    _Float16* Hs = WS;
    const int orow = w * 16 + ((l >> 4) << 2);
    const int oc = l & 15;
#pragma unroll
    for (int reg = 0; reg < 4; ++reg) {
        int grow = row0 + orow + reg;
        float d = (grow < n) ? rsqrtf((float)cursor[grow] + 1.0f) : 0.f;
#pragma unroll
        for (int cb = 0; cb < 8; ++cb)
            Hs[(orow + reg) * 136 + cb * 16 + oc] = (_Float16)(ah[cb][reg] * d);
    }
    __syncthreads();
#pragma unroll
    for (int it = 0; it < 4; ++it) {
        int i = it * 256 + tid;
        int r = i >> 4, c = (i & 15) * 8;
        if (row0 + r < n)
            *(half8*)&hs[(size_t)(row0 + r) * DIM + c] = *(const half8*)&Hs[r * 136 + c];
    }
    _Float16* pl = P + ((size_t)(blockIdx.x * 4 + w) * 64 + l) * 32;
#pragma unroll
    for (int c = 0; c < 4; ++c) {
        half8 o;
#pragma unroll
        for (int e = 0; e < 4; ++e) {
            o[e]     = (_Float16)ap[2 * c][e];
            o[4 + e] = (_Float16)ap[2 * c + 1][e];
        }
        *(half8*)&pl[c * 8] = o;
    }
}

// ---------------- mm2g: fused gather1 + GEMM2-half (LDS-staged B) ----------------
__global__ __launch_bounds__(256, 2) void k_mm2g(
    const _Float16* __restrict__ hs, const int* __restrict__ cursor,
    const int* __restrict__ srcs, const float* __restrict__ b1,
    const _Float16* __restrict__ Wp2, const _Float16* __restrict__ P,
    _Float16* __restrict__ hs2, int n) {
    __shared__ _Float16 WL[16384];     // 32KB: Wp2 rows 128..255 (frags 32..63)
    __shared__ _Float16 LS[64 * 136];  // Af (first 8192) then Hs
    const int tid = threadIdx.x;
    const int w = tid >> 6, l = tid & 63;
    const int g = tid & 15, gid = tid >> 4;
    const int row0 = blockIdx.x * 64;

    // stage W (loads fly during gather; consumed after the barrier)
#pragma unroll
    for (int i = 0; i < 8; ++i) {
        int idx = i * 256 + tid;
        *(half8*)&WL[idx * 8] = *(const half8*)&Wp2[16384 + (size_t)idx * 8];
    }

    // init acc from P (block-private; fully read before first barrier)
    f32x4 acc[8];
    const _Float16* pl = P + ((size_t)(blockIdx.x * 4 + w) * 64 + l) * 32;
#pragma unroll
    for (int c = 0; c < 4; ++c) {
        half8 pv = *(const half8*)&pl[c * 8];
#pragma unroll
        for (int e = 0; e < 4; ++e) {
            acc[2 * c][e]     = (float)pv[e];
            acc[2 * c + 1][e] = (float)pv[4 + e];
        }
    }

    // batched head loads for 4 sweeps
    int rawc4[4], sid4[4];
    half8 h4[4];
#pragma unroll
    for (int it = 0; it < 4; ++it) {
        int node = row0 + it * 16 + gid;
        bool okn = node < n;
        rawc4[it] = okn ? cursor[node] : 0;
        sid4[it] = okn ? srcs[(size_t)node * CAP + g] : 0;  // g<16<=CAP in-bounds; masked later
        h4[it] = okn ? *(const half8*)&hs[(size_t)node * DIM + g * 8] : (half8)0;
    }

#pragma unroll
    for (int it = 0; it < 4; ++it) {
        int node = row0 + it * 16 + gid;
        half8 o = 0;
        if (node < n) {
            int rawc = rawc4[it];
            int cnt = rawc > CAP ? CAP : rawc;
            float a[8];
#pragma unroll
            for (int e = 0; e < 8; ++e) a[e] = (float)h4[it][e];
            {
                int m = cnt > 16 ? 16 : cnt;
                int sidb = sid4[it];
                int j = 0;
                for (; j + 4 <= m; j += 4) {
                    int s0 = __shfl(sidb, j, 16);
                    int s1 = __shfl(sidb, j + 1, 16);
                    int s2 = __shfl(sidb, j + 2, 16);
                    int s3 = __shfl(sidb, j + 3, 16);
                    half8 v0 = *(const half8*)&hs[(size_t)s0 * DIM + g * 8];
                    half8 v1 = *(const half8*)&hs[(size_t)s1 * DIM + g * 8];
                    half8 v2 = *(const half8*)&hs[(size_t)s2 * DIM + g * 8];
                    half8 v3 = *(const half8*)&hs[(size_t)s3 * DIM + g * 8];
#pragma unroll
                    for (int e = 0; e < 8; ++e)
                        a[e] += (float)v0[e] + (float)v1[e] + (float)v2[e] + (float)v3[e];
                }
                for (; j + 2 <= m; j += 2) {
                    int s0 = __shfl(sidb, j, 16);
                    int s1 = __shfl(sidb, j + 1, 16);
                    half8 v0 = *(const half8*)&hs[(size_t)s0 * DIM + g * 8];
                    half8 v1 = *(const half8*)&hs[(size_t)s1 * DIM + g * 8];
#pragma unroll
                    for (int e = 0; e < 8; ++e) a[e] += (float)v0[e] + (float)v1[e];
                }
                if (j < m) {
                    int s0 = __shfl(sidb, j, 16);
                    half8 v0 = *(const half8*)&hs[(size_t)s0 * DIM + g * 8];
#pragma unroll
                    for (int e = 0; e < 8; ++e) a[e] += (float)v0[e];
                }
            }
            const int* sl = &srcs[(size_t)node * CAP];
            for (int base = 16; base < cnt; base += 16) {
                int m = cnt - base;
                if (m > 16) m = 16;
                int sidb = (g < m) ? sl[base + g] : 0;
                for (int j = 0; j < m; ++j) {
                    int s0 = __shfl(sidb, j, 16);
                    half8 v0 = *(const half8*)&hs[(size_t)s0 * DIM + g * 8];
#pragma unroll
                    for (int e = 0; e < 8; ++e) a[e] += (float)v0[e];
                }
            }
            float d = rsqrtf((float)rawc + 1.0f);
            const float4 bb0 = *(const float4*)&b1[g * 8];
            const float4 bb1 = *(const float4*)&b1[g * 8 + 4];
            o[0] = (_Float16)lrelu(fmaf(a[0], d, bb0.x));
            o[1] = (_Float16)lrelu(fmaf(a[1], d, bb0.y));
            o[2] = (_Float16)lrelu(fmaf(a[2], d, bb0.z));
            o[3] = (_Float16)lrelu(fmaf(a[3], d, bb0.w));
            o[4] = (_Float16)lrelu(fmaf(a[4], d, bb1.x));
            o[5] = (_Float16)lrelu(fmaf(a[5], d, bb1.y));
            o[6] = (_Float16)lrelu(fmaf(a[6], d, bb1.z));
            o[7] = (_Float16)lrelu(fmaf(a[7], d, bb1.w));
        }
        *(half8*)&LS[(((it * 4 + (g >> 2)) * 64) + (g & 3) * 16 + gid) * 8] = o;
    }
    __syncthreads();  // Af + WL both visible

#pragma unroll
    for (int kb = 0; kb < 4; ++kb) {
        half8 a = *(const half8*)&LS[((w * 4 + kb) * 64 + l) * 8];
#pragma unroll
        for (int cb = 0; cb < 8; ++cb) {
            half8 bf = *(const half8*)&WL[((kb * 8 + cb) * 64 + l) * 8];  // W2 rows 128..255
            acc[cb] = __builtin_amdgcn_mfma_f32_16x16x32_f16(a, bf, acc[cb], 0, 0, 0);
        }
    }
    __syncthreads();  // Af consumed before Hs overwrite
    const int orow = w * 16 + ((l >> 4) << 2);
    const int oc = l & 15;
#pragma unroll
    for (int reg = 0; reg < 4; ++reg) {
        int grow = row0 + orow + reg;
        float d = (grow < n) ? rsqrtf((float)cursor[grow] + 1.0f) : 0.f;
#pragma unroll
        for (int cb = 0; cb < 8; ++cb)
            LS[(orow + reg) * 136 + cb * 16 + oc] = (_Float16)(acc[cb][reg] * d);
    }
    __syncthreads();
#pragma unroll
    for (int it = 0; it < 4; ++it) {
        int i = it * 256 + tid;
        int r = i >> 4, c = (i & 15) * 8;
        if (row0 + r < n)
            *(half8*)&hs2[(size_t)(row0 + r) * DIM + c] = *(const half8*)&LS[r * 136 + c];
    }
}

// ---------------- gather2 + final projection (4-node batched, 64 nodes/block) ----------------
__global__ __launch_bounds__(256) void k_gather2(
    const _Float16* __restrict__ hs2, const int* __restrict__ cursor,
    const int* __restrict__ srcs, const float* __restrict__ b2,
    const float* __restrict__ wout, const float* __restrict__ bout,
    float* __restrict__ out, int n) {
    const int tid = threadIdx.x;
    const int g = tid & 15, gid = tid >> 4;
    const int row0 = blockIdx.x * 64;

    int rawc4[4], sid4[4];
    half8 h4[4];
#pragma unroll
    for (int it = 0; it < 4; ++it) {
        int node = row0 + it * 16 + gid;
        bool okn = node < n;
        rawc4[it] = okn ? cursor[node] : 0;
        sid4[it] = okn ? srcs[(size_t)node * CAP + g] : 0;
        h4[it] = okn ? *(const half8*)&hs2[(size_t)node * DIM + g * 8] : (half8)0;
    }

#pragma unroll
    for (int it = 0; it < 4; ++it) {
        int node = row0 + it * 16 + gid;
        if (node >= n) continue;
        int rawc = rawc4[it];
        int cnt = rawc > CAP ? CAP : rawc;
        float a[8];
#pragma unroll
        for (int e = 0; e < 8; ++e) a[e] = (float)h4[it][e];
        {
            int m = cnt > 16 ? 16 : cnt;
            int sidb = sid4[it];
            int j = 0;
            for (; j + 4 <= m; j += 4) {
                int s0 = __shfl(sidb, j, 16);
                int s1 = __shfl(sidb, j + 1, 16);
                int s2 = __shfl(sidb, j + 2, 16);
                int s3 = __shfl(sidb, j + 3, 16);
                half8 v0 = *(const half8*)&hs2[(size_t)s0 * DIM + g * 8];
                half8 v1 = *(const half8*)&hs2[(size_t)s1 * DIM + g * 8];
                half8 v2 = *(const half8*)&hs2[(size_t)s2 * DIM + g * 8];
                half8 v3 = *(const half8*)&hs2[(size_t)s3 * DIM + g * 8];
#pragma unroll
                for (int e = 0; e < 8; ++e)
                    a[e] += (float)v0[e] + (float)v1[e] + (float)v2[e] + (float)v3[e];
            }
            for (; j + 2 <= m; j += 2) {
                int s0 = __shfl(sidb, j, 16);
                int s1 = __shfl(sidb, j + 1, 16);
                half8 v0 = *(const half8*)&hs2[(size_t)s0 * DIM + g * 8];
                half8 v1 = *(const half8*)&hs2[(size_t)s1 * DIM + g * 8];
#pragma unroll
                for (int e = 0; e < 8; ++e) a[e] += (float)v0[e] + (float)v1[e];
            }
            if (j < m) {
                int s0 = __shfl(sidb, j, 16);
                half8 v0 = *(const half8*)&hs2[(size_t)s0 * DIM + g * 8];
#pragma unroll
                for (int e = 0; e < 8; ++e) a[e] += (float)v0[e];
            }
        }
        const int* sl = &srcs[(size_t)node * CAP];
        for (int base = 16; base < cnt; base += 16) {
            int m = cnt - base;
            if (m > 16) m = 16;
            int sidb = (g < m) ? sl[base + g] : 0;
            for (int j = 0; j < m; ++j) {
                int s0 = __shfl(sidb, j, 16);
                half8 v0 = *(const half8*)&hs2[(size_t)s0 * DIM + g * 8];
#pragma unroll
                for (int e = 0; e < 8; ++e) a[e] += (float)v0[e];
            }
        }
        float d = rsqrtf((float)rawc + 1.0f);
        const float4 bb0 = *(const float4*)&b2[g * 8];
        const float4 bb1 = *(const float4*)&b2[g * 8 + 4];
        const float4 wv0 = *(const float4*)&wout[g * 8];
        const float4 wv1 = *(const float4*)&wout[g * 8 + 4];
        float s = lrelu(fmaf(a[0], d, bb0.x)) * wv0.x + lrelu(fmaf(a[1], d, bb0.y)) * wv0.y +
                  lrelu(fmaf(a[2], d, bb0.z)) * wv0.z + lrelu(fmaf(a[3], d, bb0.w)) * wv0.w +
                  lrelu(fmaf(a[4], d, bb1.x)) * wv1.x + lrelu(fmaf(a[5], d, bb1.y)) * wv1.y +
                  lrelu(fmaf(a[6], d, bb1.z)) * wv1.z + lrelu(fmaf(a[7], d, bb1.w)) * wv1.w;
#pragma unroll
        for (int off = 8; off > 0; off >>= 1) s += __shfl_down(s, off, 16);
        if (g == 0) out[node] = s + bout[0];
    }
}

extern "C" void kernel_launch(void* const* d_in, const int* in_sizes, int n_in,
                              void* d_out, int out_size, void* d_ws, size_t ws_size,
                              hipStream_t stream) {
    const float* x    = (const float*)d_in[0];
    const int*   ei   = (const int*)d_in[1];
    const float* W1   = (const float*)d_in[2];
    const float* b1   = (const float*)d_in[3];
    const float* W2   = (const float*)d_in[4];
    const float* b2   = (const float*)d_in[5];
    const float* Wout = (const float*)d_in[6];
    const float* bout = (const float*)d_in[7];
    float* out = (float*)d_out;

    const int N = in_sizes[0] / DIM;
    const int E = in_sizes[1] / 2;
    const int* src = ei;      // edge_index[0]
    const int* dst = ei + E;  // edge_index[1]

    const int gb = (N + 63) / 64;
    const int eb = (E + 255) / 256;
    const long long nx = (long long)N * DIM;

    // workspace
    size_t Na = ((size_t)N + 63) & ~(size_t)63;
    int* cursor   = (int*)d_ws;                          // Na
    int* srcs     = cursor + Na;                         // N*CAP
    _Float16* Wp1 = (_Float16*)(srcs + (size_t)N * CAP); // 128*128
    _Float16* Wp2 = Wp1 + 128 * 128;                     // 256*128
    _Float16* hsb = Wp2 + 256 * 128;                     // N*128 (hs)
    _Float16* Pb  = hsb + nx;                            // gb*8192 (P -> hs2)

    (void)hipMemsetAsync(cursor, 0, (size_t)N * sizeof(int), stream);
    k_prep<<<eb + 192, 256, 0, stream>>>(src, dst, cursor, srcs, E, eb, W1, Wp1, W2, Wp2);
    k_mm1<<<gb, 256, 0, stream>>>(x, Wp1, Wp2, cursor, hsb, Pb, N);
    k_mm2g<<<gb, 256, 0, stream>>>(hsb, cursor, srcs, b1, Wp2, Pb, Pb, N);
    k_gather2<<<gb, 256, 0, stream>>>(Pb, cursor, srcs, b2, Wout, bout, out, N);
}